// Round 11
// baseline (3206.797 us; speedup 1.0000x reference)
//
#include <hip/hip_runtime.h>
#include <hip/hip_bf16.h>

typedef _Float16 f16;
typedef _Float16 half8 __attribute__((ext_vector_type(8)));
typedef float f32x4 __attribute__((ext_vector_type(4)));
typedef int i32x4 __attribute__((ext_vector_type(4)));

// B=32, S=1024, D=256, H=256, 4H=1024
// Scan r11 (hybrid pipes): waves 0-7 -> h-cols 0-127 via i8 MFMA (matrix pipe),
// waves 8-15 -> h-cols 128-255 via sdot4 (VALU pipe), one (gate,col) per lane.
// Each wave gates its own cols (r10-verified quad_perm epilogue). 1 barrier/step.

// ---------------- prep: int8 quantization of U, two compact layouts ---------
// UQm (cols with hc<128): uint4 idx ((dir*32 + g*8 + w)*4 + ks)*64 + kg*16+colr
//   packs k = ks*64+kg*16+{0..15} for gate-col g*256 + w*16 + colr.
// UQd (cols with hc>=128): dword ((dir*512 + g*128 + hc-128)*64 + kk
//   packs k = 4kk..4kk+3 for gate-col g*256 + hc.
__global__ void prep_uq_kernel(const float* __restrict__ Uf, const float* __restrict__ Ur,
                               unsigned int* __restrict__ UQm, unsigned int* __restrict__ UQd,
                               float* __restrict__ Uscale)
{
    int idx = blockIdx.x * 256 + threadIdx.x;   // (dir, c)
    if (idx >= 2048) return;
    int dir = idx >> 10, c = idx & 1023;
    const float* U = dir ? Ur : Uf;
    float m = 0.f;
    for (int k = 0; k < 256; ++k) m = fmaxf(m, fabsf(U[k * 1024 + c]));
    float sinv = (m > 0.f) ? 127.f / m : 0.f;
    int g = c >> 8, hc = c & 255;
    if (hc < 128) {
        int w = hc >> 4, colr = hc & 15, mt = g * 8 + w;
        uint4* UQm4 = (uint4*)UQm;
        for (int ks = 0; ks < 4; ++ks) {
            #pragma unroll
            for (int kg = 0; kg < 4; ++kg) {
                unsigned int wv[4];
                #pragma unroll
                for (int d = 0; d < 4; ++d) {
                    unsigned int wd = 0;
                    #pragma unroll
                    for (int e = 0; e < 4; ++e) {
                        int k = ks * 64 + kg * 16 + d * 4 + e;
                        int q = __float2int_rn(U[k * 1024 + c] * sinv);
                        wd |= ((unsigned int)(q & 0xff)) << (8 * e);
                    }
                    wv[d] = wd;
                }
                UQm4[((size_t)((dir * 32 + mt) * 4 + ks)) * 64 + kg * 16 + colr] =
                    make_uint4(wv[0], wv[1], wv[2], wv[3]);
            }
        }
    } else {
        int cc = g * 128 + (hc - 128);
        for (int kk = 0; kk < 64; ++kk) {
            unsigned int wd = 0;
            #pragma unroll
            for (int e = 0; e < 4; ++e) {
                int q = __float2int_rn(U[(kk * 4 + e) * 1024 + c] * sinv);
                wd |= ((unsigned int)(q & 0xff)) << (8 * e);
            }
            UQd[((size_t)(dir * 512 + cc)) * 64 + kk] = wd;
        }
    }
    Uscale[idx] = m / (127.f * 127.f);  // U-scale * h-dequant(1/127)
}

// ---------------- projection GEMM (unchanged, proven) -----------------------
__global__ __launch_bounds__(256) void proj_gemm_kernel(
    const float* __restrict__ x, const float* __restrict__ Wf, const float* __restrict__ Wr,
    const float* __restrict__ bfw, const float* __restrict__ brw, f16* __restrict__ G)
{
    const int nt = blockIdx.x;
    const int mt = blockIdx.y;
    const int m0 = mt * 128, n0 = nt * 128;
    const int dir = n0 >> 10, nin0 = n0 & 1023;
    const float* W   = dir ? Wr : Wf;
    const float* bia = dir ? brw : bfw;
    __shared__ f16 Asm[128][40];
    __shared__ f16 Bsm[128][40];
    const int t = threadIdx.x;
    const int lane = t & 63, wave = t >> 6;
    const int wr = wave >> 1, wc = wave & 1;
    f32x4 acc[4][4] = {};
    for (int k0 = 0; k0 < 256; k0 += 32) {
        #pragma unroll
        for (int e = 0; e < 16; ++e) {
            int idx = e * 256 + t;
            int r = idx >> 5, kk = idx & 31;
            Asm[r][kk] = (f16)x[(size_t)(m0 + r) * 256 + (k0 + kk)];
        }
        #pragma unroll
        for (int e = 0; e < 16; ++e) {
            int idx = e * 256 + t;
            int col = idx & 127, kr = idx >> 7;
            Bsm[col][kr] = (f16)W[(size_t)(k0 + kr) * 1024 + (nin0 + col)];
        }
        __syncthreads();
        const int l15 = lane & 15, kb = (lane >> 4) * 8;
        half8 af[4], bfr[4];
        #pragma unroll
        for (int fr = 0; fr < 4; ++fr) af[fr]  = *(const half8*)&Asm[wr * 64 + fr * 16 + l15][kb];
        #pragma unroll
        for (int fc = 0; fc < 4; ++fc) bfr[fc] = *(const half8*)&Bsm[wc * 64 + fc * 16 + l15][kb];
        #pragma unroll
        for (int fr = 0; fr < 4; ++fr)
            #pragma unroll
            for (int fc = 0; fc < 4; ++fc)
                acc[fr][fc] = __builtin_amdgcn_mfma_f32_16x16x32_f16(af[fr], bfr[fc], acc[fr][fc], 0, 0, 0);
        __syncthreads();
    }
    const int row4 = (lane >> 4) * 4, c15 = lane & 15;
    #pragma unroll
    for (int fr = 0; fr < 4; ++fr)
        #pragma unroll
        for (int fc = 0; fc < 4; ++fc) {
            int rbase = m0 + wr * 64 + fr * 16 + row4;
            int cidx  = n0 + wc * 64 + fc * 16 + c15;
            float bv = bia[cidx & 1023];
            #pragma unroll
            for (int i = 0; i < 4; ++i)
                G[(size_t)(rbase + i) * 2048 + cidx] = (f16)(acc[fr][fc][i] + bv);
        }
}

// ---------------- scan ------------------------------------------------------
__device__ __forceinline__ int dot4i8(unsigned int a, unsigned int b, int c) {
#if __has_builtin(__builtin_amdgcn_sdot4)
    return __builtin_amdgcn_sdot4(a, b, c, false);
#else
    c += (int)(signed char)(a)       * (int)(signed char)(b);
    c += (int)(signed char)(a >> 8)  * (int)(signed char)(b >> 8);
    c += (int)(signed char)(a >> 16) * (int)(signed char)(b >> 16);
    c += (int)(signed char)(a >> 24) * (int)(signed char)(b >> 24);
    return c;
#endif
}

template<int PAT>
__device__ __forceinline__ float qb(float v) {   // quad_perm broadcast
    return __int_as_float(__builtin_amdgcn_mov_dpp(__float_as_int(v), PAT, 0xF, 0xF, true));
}

#define LGKM_BARRIER() do { \
    asm volatile("s_waitcnt lgkmcnt(0)\n\ts_barrier" ::: "memory"); \
    __builtin_amdgcn_sched_barrier(0); \
} while (0)

__global__
__attribute__((amdgpu_flat_work_group_size(1024, 1024)))
__attribute__((amdgpu_waves_per_eu(4, 4)))
void scan_kernel(
    const f16* __restrict__ G, const unsigned int* __restrict__ UQm,
    const unsigned int* __restrict__ UQd, const float* __restrict__ Uscale,
    float* __restrict__ out)
{
    const int wg = blockIdx.x;
    const int dir = wg >> 5, b = wg & 31;
    const int tid = threadIdx.x;
    const int wave = tid >> 6, lane = tid & 63;
    const bool mfma_w = (wave < 8);
    const int colq = lane >> 2, gate = lane & 3;
    const int hc = mfma_w ? (wave * 16 + colq) : (128 + (wave - 8) * 16 + colq);

    __shared__ __align__(16) unsigned int hq[128];  // 2 bufs x 256B int8 h
    __shared__ __align__(16) int scr[512];          // mfma waves: 16 cols x 4 gates

    if (tid < 64) hq[tid] = 0u;                     // buf0 = h0 = 0

    // ---- per-path U residency ----
    i32x4 uf0[4], uf1[4], uf2[4], uf3[4];           // mfma path (AGPR-native)
    uint4 ureg[16];                                 // dot path
    if (mfma_w) {
        const i32x4* UQm4 = (const i32x4*)UQm;
        #pragma unroll
        for (int ks = 0; ks < 4; ++ks) {
            uf0[ks] = UQm4[((size_t)((dir * 32 + ( 0 + wave)) * 4 + ks)) * 64 + lane];
            uf1[ks] = UQm4[((size_t)((dir * 32 + ( 8 + wave)) * 4 + ks)) * 64 + lane];
            uf2[ks] = UQm4[((size_t)((dir * 32 + (16 + wave)) * 4 + ks)) * 64 + lane];
            uf3[ks] = UQm4[((size_t)((dir * 32 + (24 + wave)) * 4 + ks)) * 64 + lane];
        }
    } else {
        const int cc = gate * 128 + (wave - 8) * 16 + colq;
        const uint4* up = (const uint4*)(UQd + ((size_t)(dir * 512 + cc)) * 64);
        #pragma unroll
        for (int kkk = 0; kkk < 16; ++kkk)
            asm volatile("global_load_dwordx4 %0, %1, off offset:%2"
                         : "=v"(ureg[kkk]) : "v"(up), "i"(kkk * 16));
        asm volatile("s_waitcnt vmcnt(0)" ::: "memory");
        __builtin_amdgcn_sched_barrier(0);
    }

    const float uscl = Uscale[dir * 1024 + gate * 256 + hc];

    // per-lane xW stream for (gate, hc)
    const f16* Gl = G + (size_t)b * 1024 * 2048 + dir * 1024 + gate * 256 + hc;
    float* outp = out + (size_t)b * 1024 * 512 + dir * 256 + hc;
    const int s0 = dir ? 1023 : 0;
    float xw = (float)Gl[(size_t)s0 * 2048];
    float c_state = 0.f;                            // replicated per quad
    __syncthreads();

    const char* hqb = (const char*)hq;
    signed char* hqw = (signed char*)hq;
    int* scrw = scr + (mfma_w ? wave * 64 : 0);
    const int arow = (lane >> 4) << 4;              // A-frag byte offset
    int p = 0;

    for (int t = 0; t < 1024; ++t) {
        const int s  = dir ? (1023 - t) : t;
        const int tn = (t < 1023) ? (t + 1) : t;
        const int sn = dir ? (1023 - tn) : tn;
        f16 xn = Gl[(size_t)sn * 2048];             // prefetch next xW

        float pre;
        if (mfma_w) {
            // h @ U for tiles {g*8+wave}: A = h broadcast; row 0 = result
            i32x4 acc0 = {0,0,0,0}, acc1 = {0,0,0,0}, acc2 = {0,0,0,0}, acc3 = {0,0,0,0};
            #pragma unroll
            for (int ks = 0; ks < 4; ++ks) {
                i32x4 a = *(const i32x4*)(hqb + p * 256 + ks * 64 + arow);
                acc0 = __builtin_amdgcn_mfma_i32_16x16x64_i8(a, uf0[ks], acc0, 0, 0, 0);
                acc1 = __builtin_amdgcn_mfma_i32_16x16x64_i8(a, uf1[ks], acc1, 0, 0, 0);
                acc2 = __builtin_amdgcn_mfma_i32_16x16x64_i8(a, uf2[ks], acc2, 0, 0, 0);
                acc3 = __builtin_amdgcn_mfma_i32_16x16x64_i8(a, uf3[ks], acc3, 0, 0, 0);
            }
            if (lane < 16) {                        // dump raw {i,f,g,o} per col
                i32x4 pv; pv[0] = acc0[0]; pv[1] = acc1[0]; pv[2] = acc2[0]; pv[3] = acc3[0];
                *(i32x4*)(scrw + lane * 4) = pv;
            }
            asm volatile("s_waitcnt lgkmcnt(0)" ::: "memory");  // wave-local RAW
            __builtin_amdgcn_sched_barrier(0);
            pre = (float)scrw[colq * 4 + gate] * uscl + xw;
        } else {
            // sdot4 over my (gate,col)'s U column; chunked (r5-verified)
            const uint4* hp4 = (const uint4*)(hqb + p * 256);
            int i0 = 0, i1 = 0, i2 = 0, i3 = 0;
            #pragma unroll
            for (int ch = 0; ch < 4; ++ch) {
                uint4 ha = hp4[ch * 4 + 0];
                uint4 hb = hp4[ch * 4 + 1];
                uint4 hc4 = hp4[ch * 4 + 2];
                uint4 hd = hp4[ch * 4 + 3];
                i0 = dot4i8(ureg[ch * 4 + 0].x, ha.x, i0);
                i1 = dot4i8(ureg[ch * 4 + 0].y, ha.y, i1);
                i2 = dot4i8(ureg[ch * 4 + 0].z, ha.z, i2);
                i3 = dot4i8(ureg[ch * 4 + 0].w, ha.w, i3);
                i0 = dot4i8(ureg[ch * 4 + 1].x, hb.x, i0);
                i1 = dot4i8(ureg[ch * 4 + 1].y, hb.y, i1);
                i2 = dot4i8(ureg[ch * 4 + 1].z, hb.z, i2);
                i3 = dot4i8(ureg[ch * 4 + 1].w, hb.w, i3);
                i0 = dot4i8(ureg[ch * 4 + 2].x, hc4.x, i0);
                i1 = dot4i8(ureg[ch * 4 + 2].y, hc4.y, i1);
                i2 = dot4i8(ureg[ch * 4 + 2].z, hc4.z, i2);
                i3 = dot4i8(ureg[ch * 4 + 2].w, hc4.w, i3);
                i0 = dot4i8(ureg[ch * 4 + 3].x, hd.x, i0);
                i1 = dot4i8(ureg[ch * 4 + 3].y, hd.y, i1);
                i2 = dot4i8(ureg[ch * 4 + 3].z, hd.z, i2);
                i3 = dot4i8(ureg[ch * 4 + 3].w, hd.w, i3);
                __builtin_amdgcn_sched_barrier(0);
            }
            pre = (float)((i0 + i1) + (i2 + i3)) * uscl + xw;
        }

        // unified quad-gate epilogue (r10-verified)
        float a2 = (gate == 2) ? (pre + pre) : -pre;
        float E  = __expf(a2);
        float r  = __fdividef(1.f, E + 1.f);
        float v  = (gate == 2) ? (1.f - 2.f * r) : r;
        float b0 = qb<0x00>(v), b1 = qb<0x55>(v), b2 = qb<0xAA>(v), b3 = qb<0xFF>(v);
        c_state = b1 * c_state + b0 * b2;
        float e2 = __expf(c_state + c_state);
        float th = 1.f - __fdividef(2.f, e2 + 1.f);
        float h  = b3 * th;

        if (gate == 0) outp[(size_t)s * 512] = h;
        if (gate == 1) hqw[(p ^ 1) * 256 + hc] = (signed char)__float2int_rn(h * 127.f);

        LGKM_BARRIER();                             // new h visible to all
        p ^= 1;
        xw = (float)xn;
    }
}

extern "C" void kernel_launch(void* const* d_in, const int* in_sizes, int n_in,
                              void* d_out, int out_size, void* d_ws, size_t ws_size,
                              hipStream_t stream) {
    const float* x  = (const float*)d_in[0];
    const float* Wf = (const float*)d_in[1];
    const float* Uf = (const float*)d_in[2];
    const float* bf = (const float*)d_in[3];
    const float* Wr = (const float*)d_in[4];
    const float* Ur = (const float*)d_in[5];
    const float* br = (const float*)d_in[6];
    float* out = (float*)d_out;

    char* ws = (char*)d_ws;
    unsigned int* UQm = (unsigned int*)ws;                        // 256 KB
    unsigned int* UQd = (unsigned int*)(ws + (size_t)256 * 1024); // 256 KB
    float* Uscale     = (float*)(ws + (size_t)512 * 1024);        // 8 KB
    f16* G            = (f16*)(ws + (size_t)1024 * 1024);         // 128 MB

    prep_uq_kernel<<<8, 256, 0, stream>>>(Uf, Ur, UQm, UQd, Uscale);
    dim3 gg(16, 256);
    proj_gemm_kernel<<<gg, 256, 0, stream>>>(x, Wf, Wr, bf, br, G);
    scan_kernel<<<64, 1024, 0, stream>>>(G, UQm, UQd, Uscale, out);
}

// Round 12
// 1021.260 us; speedup vs baseline: 3.1400x; 3.1400x over previous
//
#include <hip/hip_runtime.h>
#include <hip/hip_bf16.h>

typedef _Float16 f16;
typedef _Float16 half8 __attribute__((ext_vector_type(8)));
typedef float f32x4 __attribute__((ext_vector_type(4)));
typedef int i32x4 __attribute__((ext_vector_type(4)));

// B=32, S=1024, D=256, H=256, 4H=1024
// Scan r12: i8-MFMA recurrent matmul + quad-gate epilogue via ds_bpermute
// (no scr LDS roundtrip), 1 lgkm-barrier/step, double-buffered h.
// Wave w owns tiles {g*16+w} (all 4 gates of h-cols w*16..w*16+15).
// Lane l = gate (l&3) of h-col w*16+(l>>2); quads combine via DPP quad_perm.

// ---------------- prep: per-column int8 quantization of U (mfma layout) -----
// UQm uint4 index: ((dir*64 + tile)*4 + ks)*64 + kg*16 + colr
//   holds k = ks*64 + kg*16 + {0..15} (16 int8) for col = tile*16 + colr.
__global__ void prep_uq_kernel(const float* __restrict__ Uf, const float* __restrict__ Ur,
                               unsigned int* __restrict__ UQm, float* __restrict__ Uscale)
{
    int idx = blockIdx.x * 256 + threadIdx.x;   // (dir, c)
    if (idx >= 2048) return;
    int dir = idx >> 10, c = idx & 1023;
    const float* U = dir ? Ur : Uf;
    float m = 0.f;
    for (int k = 0; k < 256; ++k) m = fmaxf(m, fabsf(U[k * 1024 + c]));
    float sinv = (m > 0.f) ? 127.f / m : 0.f;
    int tile = c >> 4, colr = c & 15;
    uint4* UQm4 = (uint4*)UQm;
    for (int ks = 0; ks < 4; ++ks) {
        #pragma unroll
        for (int kg = 0; kg < 4; ++kg) {
            unsigned int w[4];
            #pragma unroll
            for (int d = 0; d < 4; ++d) {
                unsigned int wd = 0;
                #pragma unroll
                for (int e = 0; e < 4; ++e) {
                    int k = ks * 64 + kg * 16 + d * 4 + e;
                    int q = __float2int_rn(U[k * 1024 + c] * sinv);
                    wd |= ((unsigned int)(q & 0xff)) << (8 * e);
                }
                w[d] = wd;
            }
            UQm4[((size_t)((dir * 64 + tile) * 4 + ks)) * 64 + kg * 16 + colr] =
                make_uint4(w[0], w[1], w[2], w[3]);
        }
    }
    Uscale[idx] = m / (127.f * 127.f);  // U-scale * h-dequant(1/127)
}

// ---------------- projection GEMM (unchanged, proven) -----------------------
__global__ __launch_bounds__(256) void proj_gemm_kernel(
    const float* __restrict__ x, const float* __restrict__ Wf, const float* __restrict__ Wr,
    const float* __restrict__ bfw, const float* __restrict__ brw, f16* __restrict__ G)
{
    const int nt = blockIdx.x;
    const int mt = blockIdx.y;
    const int m0 = mt * 128, n0 = nt * 128;
    const int dir = n0 >> 10, nin0 = n0 & 1023;
    const float* W   = dir ? Wr : Wf;
    const float* bia = dir ? brw : bfw;
    __shared__ f16 Asm[128][40];
    __shared__ f16 Bsm[128][40];
    const int t = threadIdx.x;
    const int lane = t & 63, wave = t >> 6;
    const int wr = wave >> 1, wc = wave & 1;
    f32x4 acc[4][4] = {};
    for (int k0 = 0; k0 < 256; k0 += 32) {
        #pragma unroll
        for (int e = 0; e < 16; ++e) {
            int idx = e * 256 + t;
            int r = idx >> 5, kk = idx & 31;
            Asm[r][kk] = (f16)x[(size_t)(m0 + r) * 256 + (k0 + kk)];
        }
        #pragma unroll
        for (int e = 0; e < 16; ++e) {
            int idx = e * 256 + t;
            int col = idx & 127, kr = idx >> 7;
            Bsm[col][kr] = (f16)W[(size_t)(k0 + kr) * 1024 + (nin0 + col)];
        }
        __syncthreads();
        const int l15 = lane & 15, kb = (lane >> 4) * 8;
        half8 af[4], bfr[4];
        #pragma unroll
        for (int fr = 0; fr < 4; ++fr) af[fr]  = *(const half8*)&Asm[wr * 64 + fr * 16 + l15][kb];
        #pragma unroll
        for (int fc = 0; fc < 4; ++fc) bfr[fc] = *(const half8*)&Bsm[wc * 64 + fc * 16 + l15][kb];
        #pragma unroll
        for (int fr = 0; fr < 4; ++fr)
            #pragma unroll
            for (int fc = 0; fc < 4; ++fc)
                acc[fr][fc] = __builtin_amdgcn_mfma_f32_16x16x32_f16(af[fr], bfr[fc], acc[fr][fc], 0, 0, 0);
        __syncthreads();
    }
    const int row4 = (lane >> 4) * 4, c15 = lane & 15;
    #pragma unroll
    for (int fr = 0; fr < 4; ++fr)
        #pragma unroll
        for (int fc = 0; fc < 4; ++fc) {
            int rbase = m0 + wr * 64 + fr * 16 + row4;
            int cidx  = n0 + wc * 64 + fc * 16 + c15;
            float bv = bia[cidx & 1023];
            #pragma unroll
            for (int i = 0; i < 4; ++i)
                G[(size_t)(rbase + i) * 2048 + cidx] = (f16)(acc[fr][fc][i] + bv);
        }
}

// ---------------- scan ------------------------------------------------------
template<int PAT>
__device__ __forceinline__ float qb(float v) {   // quad_perm broadcast
    return __int_as_float(__builtin_amdgcn_mov_dpp(__float_as_int(v), PAT, 0xF, 0xF, true));
}

#define LGKM_BARRIER() do { \
    asm volatile("s_waitcnt lgkmcnt(0)\n\ts_barrier" ::: "memory"); \
    __builtin_amdgcn_sched_barrier(0); \
} while (0)

__global__
__attribute__((amdgpu_flat_work_group_size(1024, 1024)))
__attribute__((amdgpu_waves_per_eu(4, 4)))
void scan_kernel(
    const f16* __restrict__ G, const unsigned int* __restrict__ UQm,
    const float* __restrict__ Uscale, float* __restrict__ out)
{
    const int wg = blockIdx.x;
    const int dir = wg >> 5, b = wg & 31;
    const int tid = threadIdx.x;
    const int wave = tid >> 6, lane = tid & 63;
    const int colq = lane >> 2, gate = lane & 3;    // lane -> (col, gate)
    const int mycol = wave * 16 + colq;

    __shared__ __align__(16) unsigned int hq[128];  // 2 bufs x 256B int8 h

    if (tid < 64) hq[tid] = 0u;                     // buf0 = h0 = 0

    // B-fragments: gate g of my h-cols -> tile g*16+wave (64 regs, AGPR-ok)
    const i32x4* UQm4 = (const i32x4*)UQm;
    i32x4 uf0[4], uf1[4], uf2[4], uf3[4];
    #pragma unroll
    for (int ks = 0; ks < 4; ++ks) {
        uf0[ks] = UQm4[((size_t)((dir * 64 + ( 0 + wave)) * 4 + ks)) * 64 + lane];
        uf1[ks] = UQm4[((size_t)((dir * 64 + (16 + wave)) * 4 + ks)) * 64 + lane];
        uf2[ks] = UQm4[((size_t)((dir * 64 + (32 + wave)) * 4 + ks)) * 64 + lane];
        uf3[ks] = UQm4[((size_t)((dir * 64 + (48 + wave)) * 4 + ks)) * 64 + lane];
    }

    // per-lane dequant scale for (gate, mycol)
    const float uscl = Uscale[dir * 1024 + gate * 256 + mycol];

    // per-lane xW stream: G[s][dir*1024 + gate*256 + mycol]
    const f16* Gl = G + (size_t)b * 1024 * 2048 + dir * 1024 + gate * 256 + mycol;
    float* outp = out + (size_t)b * 1024 * 512 + dir * 256 + mycol;

    const int s0 = dir ? 1023 : 0;
    float xw = (float)Gl[(size_t)s0 * 2048];
    float c_state = 0.f;                            // replicated per quad
    __syncthreads();

    const char* hqb = (const char*)hq;
    signed char* hqw = (signed char*)hq;
    const int arow = (lane >> 4) << 4;              // A-frag byte offset
    const int baddr = lane & ~3;                    // bpermute byte addr = (l>>2)*4
    int p = 0;

    for (int t = 0; t < 1024; ++t) {
        const int s  = dir ? (1023 - t) : t;
        const int tn = (t < 1023) ? (t + 1) : t;
        const int sn = dir ? (1023 - tn) : tn;
        f16 xn = Gl[(size_t)sn * 2048];             // prefetch next xW

        // h @ U, exact i32: A = h broadcast across rows; all C rows identical
        i32x4 acc0 = {0,0,0,0}, acc1 = {0,0,0,0}, acc2 = {0,0,0,0}, acc3 = {0,0,0,0};
        #pragma unroll
        for (int ks = 0; ks < 4; ++ks) {
            i32x4 a = *(const i32x4*)(hqb + p * 256 + ks * 64 + arow);
            acc0 = __builtin_amdgcn_mfma_i32_16x16x64_i8(a, uf0[ks], acc0, 0, 0, 0);
            acc1 = __builtin_amdgcn_mfma_i32_16x16x64_i8(a, uf1[ks], acc1, 0, 0, 0);
            acc2 = __builtin_amdgcn_mfma_i32_16x16x64_i8(a, uf2[ks], acc2, 0, 0, 0);
            acc3 = __builtin_amdgcn_mfma_i32_16x16x64_i8(a, uf3[ks], acc3, 0, 0, 0);
        }

        // every lane holds acc_g[0] = pre(col lane&15, gate g). Lane l needs
        // (col l>>2, gate l&3): 4 bpermutes (pull from lane l>>2) + select.
        int r0 = __builtin_amdgcn_ds_bpermute(baddr, acc0[0]);
        int r1 = __builtin_amdgcn_ds_bpermute(baddr, acc1[0]);
        int r2 = __builtin_amdgcn_ds_bpermute(baddr, acc2[0]);
        int r3 = __builtin_amdgcn_ds_bpermute(baddr, acc3[0]);
        int iv01 = (gate & 1) ? r1 : r0;
        int iv23 = (gate & 1) ? r3 : r2;
        int iv   = (gate & 2) ? iv23 : iv01;

        float pre = (float)iv * uscl + xw;
        // unified nonlinearity: gate 2 -> tanh, else sigmoid
        float a2 = (gate == 2) ? (pre + pre) : -pre;
        float E  = __expf(a2);
        float r  = __fdividef(1.f, E + 1.f);
        float v  = (gate == 2) ? (1.f - 2.f * r) : r;
        // quad combine: b0=sig_i, b1=sig_f, b2=tanh_g, b3=sig_o
        float b0 = qb<0x00>(v), b1 = qb<0x55>(v), b2 = qb<0xAA>(v), b3 = qb<0xFF>(v);
        c_state = b1 * c_state + b0 * b2;
        float e2 = __expf(c_state + c_state);
        float th = 1.f - __fdividef(2.f, e2 + 1.f);
        float h  = b3 * th;

        if (gate == 0) outp[(size_t)s * 512] = h;
        if (gate == 1) hqw[(p ^ 1) * 256 + mycol] = (signed char)__float2int_rn(h * 127.f);

        LGKM_BARRIER();                             // new h visible to all
        p ^= 1;
        xw = (float)xn;
    }
}

extern "C" void kernel_launch(void* const* d_in, const int* in_sizes, int n_in,
                              void* d_out, int out_size, void* d_ws, size_t ws_size,
                              hipStream_t stream) {
    const float* x  = (const float*)d_in[0];
    const float* Wf = (const float*)d_in[1];
    const float* Uf = (const float*)d_in[2];
    const float* bf = (const float*)d_in[3];
    const float* Wr = (const float*)d_in[4];
    const float* Ur = (const float*)d_in[5];
    const float* br = (const float*)d_in[6];
    float* out = (float*)d_out;

    char* ws = (char*)d_ws;
    unsigned int* UQm = (unsigned int*)ws;                      // 512 KB
    float* Uscale     = (float*)(ws + (size_t)512 * 1024);      // 8 KB
    f16* G            = (f16*)(ws + (size_t)1024 * 1024);       // 128 MB

    prep_uq_kernel<<<8, 256, 0, stream>>>(Uf, Ur, UQm, Uscale);
    dim3 gg(16, 256);
    proj_gemm_kernel<<<gg, 256, 0, stream>>>(x, Wf, Wr, bf, br, G);
    scan_kernel<<<64, 1024, 0, stream>>>(G, UQm, Uscale, out);
}